// Round 1
// 250.708 us; speedup vs baseline: 1.0224x; 1.0224x over previous
//
#include <hip/hip_runtime.h>
#include <cstdint>
#include <cstddef>

// LSTM cell: B=16384, IN=HID=512.
// R8: 256x256 tile, BK=64, 8 waves (2M x 4N, per-wave 128x64), 4-phase
// K-step schedule with counted vmcnt(6) (never 0 in the loop), raw
// s_barrier, setprio around MFMA clusters (T3+T4+T5). LDS stored as
// k-chunked [256][32] regions so every ds_read_b128 covers contiguous
// 1024 B -> bank-conflict-free without swizzle (gload_lds stays linear).
// Region pipeline (steady state, per K-tile t, regions = 16 KB = 2 instr/thr):
//   ph0: read Akc0+Bkc0(t); stage Akc1(t+1)->buf[t+1]   (freed at t-1.ph3)
//   ph1: read Akc0(t) h1 ;  stage Bkc0(t+2)->buf[t]     (freed at t.ph0)
//   ph2: read Akc1+Bkc1(t); stage Akc0(t+2)->buf[t]     (freed at t.ph1)
//   ph3: read Akc1(t) h1 ;  stage Bkc1(t+2)->buf[t]     (freed at t.ph2)
//   vmcnt(6) at ph3 end = allow 3 newest regions outstanding -> all of
//   tile t+1 (through Akc1(t+1)) complete before tile t+1 reads it.
// Tail: stage source K-tile clamped to NT-1; destinations follow pipeline
// slots, which are provably free/never-read-again -> safe, uniform counts.

#define BATCH 16384
#define KDIM  1024
#define NPK   2048
#define HIDN  512

#define BM 256
#define BN 256
#define BK 64
#define NT (KDIM / BK)   // 16

typedef __bf16 bf16x8 __attribute__((ext_vector_type(8)));
typedef float  f32x4  __attribute__((ext_vector_type(4)));

__device__ __forceinline__ unsigned short f2bf(float f) {
  unsigned int u = __builtin_bit_cast(unsigned int, f);
  u += 0x7fffu + ((u >> 16) & 1u);   // RNE
  return (unsigned short)(u >> 16);
}

__device__ __forceinline__ float fast_sigmoid(float x) {
  return __builtin_amdgcn_rcpf(1.0f + __expf(-x));
}
__device__ __forceinline__ float fast_tanh(float x) {
  return 1.0f - 2.0f * __builtin_amdgcn_rcpf(1.0f + __expf(2.0f * x));
}

// async global->LDS, 16 B per lane; LDS dest = wave-uniform base + lane*16
__device__ __forceinline__ void gload_lds16(const void* gp, void* lds_wave_base) {
  auto g = (const __attribute__((address_space(1))) unsigned int*)(unsigned long long)gp;
  auto l = (__attribute__((address_space(3))) unsigned int*)
           (unsigned int)(unsigned long long)lds_wave_base;
  __builtin_amdgcn_global_load_lds(g, l, 16, 0, 0);
}

// ---------------- prep kernels (unchanged) ----------------
__global__ __launch_bounds__(256) void pack_a(const float* __restrict__ x,
                                              const float* __restrict__ h,
                                              unsigned short* __restrict__ A) {
  int c = blockIdx.x * 256 + threadIdx.x;   // chunk of 8 elements
  int idx = c << 3;
  int b = idx >> 10;          // row
  int k = idx & 1023;         // col
  const float* src = (k < 512) ? (x + (size_t)b * 512 + k)
                               : (h + (size_t)b * 512 + (k - 512));
  float4 lo = ((const float4*)src)[0];
  float4 hi = ((const float4*)src)[1];
  union { unsigned short s[8]; uint4 u; } o;
  o.s[0]=f2bf(lo.x); o.s[1]=f2bf(lo.y); o.s[2]=f2bf(lo.z); o.s[3]=f2bf(lo.w);
  o.s[4]=f2bf(hi.x); o.s[5]=f2bf(hi.y); o.s[6]=f2bf(hi.z); o.s[7]=f2bf(hi.w);
  ((uint4*)A)[c] = o.u;
}

struct GatePtrs {
  const float* wx[4];  // gate order: i, g, f, o
  const float* wh[4];
  const float* bx[4];
  const float* bh[4];
};

// W row-major bf16 [2048][1024], rows packed r = b*128 + wn*64 + gate*16 + jl,
// j = b*32 + wn*16 + jl.
__global__ __launch_bounds__(256) void pack_w(GatePtrs P,
                                              unsigned short* __restrict__ W,
                                              float* __restrict__ bias) {
  int c = blockIdx.x * 256 + threadIdx.x;   // chunk of 8, 128 chunks per row
  int r = c >> 7;
  int k = (c & 127) << 3;
  int b    = r >> 7;
  int rem  = r & 127;
  int wn   = (rem >> 6) & 1;
  int gate = (rem >> 4) & 3;
  int jl   = rem & 15;
  int j = b * 32 + wn * 16 + jl;
  const float* src = (k < 512) ? (P.wx[gate] + (size_t)j * 512 + k)
                               : (P.wh[gate] + (size_t)j * 512 + (k - 512));
  float4 lo = ((const float4*)src)[0];
  float4 hi = ((const float4*)src)[1];
  union { unsigned short s[8]; uint4 u; } o;
  o.s[0]=f2bf(lo.x); o.s[1]=f2bf(lo.y); o.s[2]=f2bf(lo.z); o.s[3]=f2bf(lo.w);
  o.s[4]=f2bf(hi.x); o.s[5]=f2bf(hi.y); o.s[6]=f2bf(hi.z); o.s[7]=f2bf(hi.w);
  ((uint4*)W)[c] = o.u;
  if ((c & 127) == 0) bias[r] = P.bx[gate][j] + P.bh[gate][j];
}

// ---------------- fused GEMM + LSTM epilogue ----------------

__global__ __launch_bounds__(512, 2) void lstm_gemm(
    const unsigned short* __restrict__ A,    // [16384,1024] bf16 row-major
    const unsigned short* __restrict__ W,    // [2048,1024] bf16 packed rows
    const float* __restrict__ bias,          // [2048] packed
    const float* __restrict__ Cin,           // [16384,512]
    float* __restrict__ Hout,                // [16384,512]
    float* __restrict__ Cout) {              // [16384,512]
  // 2 buffers x { Akc0, Akc1, Bkc0, Bkc1 } regions, each [256 rows][32 cols]
  // bf16 = 8192 ushorts = 16 KB. Total 128 KB -> 1 block/CU.
  __shared__ __align__(16) unsigned short lds[2 * 32768];

  const int tid  = threadIdx.x;
  const int lane = tid & 63;
  const int wv   = tid >> 6;     // 0..7
  const int wm   = wv >> 2;      // 0..1 (wave row; 2 x 128 = 256)
  const int wn   = wv & 3;       // 0..3 (wave col; 4 x 64  = 256)

  // XCD-aware swizzle: 512 blocks, nwg%8==0 -> simple swizzle bijective.
  // XCD x gets all 8 bn for bm in {x, x+8, ...}: shares 8 W panels (4 MB,
  // L2-resident across its bm iterations) + one A panel per bm.
  const int lin = blockIdx.x;    // 0..511
  const int xcd = lin & 7;
  const int idx = lin >> 3;
  const int bn  = idx & 7;       // 0..7
  const int bm  = (idx >> 3) * 8 + xcd;  // 0..63

  // ---- staging addressing: one region = 2 gload_lds16 per thread ----
  // instr i of wave wv covers rows wv*32 + i*16 + (lane>>2), cols (lane&3)*8.
  const int srow = lane >> 2;            // 0..15
  const int scol = (lane & 3) << 3;      // 0,8,16,24
  const unsigned short* gA = A + (size_t)(bm * 256 + wv * 32 + srow) * KDIM + scol;
  const unsigned short* gB = W + (size_t)(bn * 256 + wv * 32 + srow) * KDIM + scol;
  const int lA = wv * 1024;              // wave's 32-row slab (ushorts) in a region

#define REG_A(b, c) ((b) * 32768 + (c) * 8192)
#define REG_B(b, c) ((b) * 32768 + 16384 + (c) * 8192)

#define STAGE_A(b, c, tt) do {                                      \
    const unsigned short* s_ = gA + (tt) * 64 + (c) * 32;           \
    gload_lds16(s_,            &lds[REG_A(b, c) + lA]);             \
    gload_lds16(s_ + 16 * KDIM, &lds[REG_A(b, c) + lA + 512]);      \
  } while (0)
#define STAGE_B(b, c, tt) do {                                      \
    const unsigned short* s_ = gB + (tt) * 64 + (c) * 32;           \
    gload_lds16(s_,            &lds[REG_B(b, c) + lA]);             \
    gload_lds16(s_ + 16 * KDIM, &lds[REG_B(b, c) + lA + 512]);      \
  } while (0)

  // ---- fragment addressing (contiguous 1024 B per 64-lane read) ----
  const int lrow = lane & 15;
  const int kg   = (lane >> 4) << 3;     // k-offset (ushorts) within 32-col chunk
  const int aoff = wm * 4096 + lrow * 32 + kg;   // + h*2048 + mi*512
  const int boff = wn * 2048 + lrow * 32 + kg;   // + ni*512

  f32x4 acc[8][4] = {};   // [m: h*4+mi][gate ni]; 128 VGPRs
  bf16x8 af[4], bfr[4];

#define LOAD_AF(b, c, h) do {                                                  \
    _Pragma("unroll")                                                          \
    for (int mi = 0; mi < 4; ++mi)                                             \
      af[mi] = *reinterpret_cast<const bf16x8*>(                               \
          &lds[REG_A(b, c) + aoff + (h) * 2048 + mi * 512]);                   \
  } while (0)
#define LOAD_BF(b, c) do {                                                     \
    _Pragma("unroll")                                                          \
    for (int ni = 0; ni < 4; ++ni)                                             \
      bfr[ni] = *reinterpret_cast<const bf16x8*>(                              \
          &lds[REG_B(b, c) + boff + ni * 512]);                                \
  } while (0)
#define MFMA_BLK(h) do {                                                       \
    __builtin_amdgcn_s_setprio(1);                                             \
    _Pragma("unroll")                                                          \
    for (int mi = 0; mi < 4; ++mi)                                             \
      _Pragma("unroll")                                                        \
      for (int ni = 0; ni < 4; ++ni)                                           \
        acc[(h) * 4 + mi][ni] = __builtin_amdgcn_mfma_f32_16x16x32_bf16(       \
            af[mi], bfr[ni], acc[(h) * 4 + mi][ni], 0, 0, 0);                  \
    __builtin_amdgcn_s_setprio(0);                                             \
  } while (0)

#define BAR()  __builtin_amdgcn_s_barrier()
#define SCB()  __builtin_amdgcn_sched_barrier(0)
// rule #18: sched_barrier(0) after lgkmcnt(0) so MFMA can't hoist above it
#define WAIT_LGKM0() do { asm volatile("s_waitcnt lgkmcnt(0)" ::: "memory"); SCB(); } while (0)

  // ---- prologue: issue order defines vmcnt arithmetic ----
  // [Bkc0(0), Akc0(0), Bkc1(0), Akc1(0), Bkc0(1), Akc0(1), Bkc1(1)]
  // vmcnt(6) -> all but newest 3 regions done -> tile 0 fully resident.
  STAGE_B(0, 0, 0); STAGE_A(0, 0, 0); STAGE_B(0, 1, 0); STAGE_A(0, 1, 0);
  STAGE_B(1, 0, 1); STAGE_A(1, 0, 1); STAGE_B(1, 1, 1);
  asm volatile("s_waitcnt vmcnt(6)" ::: "memory");
  BAR(); SCB();

#pragma unroll 2
  for (int t = 0; t < NT; ++t) {
    const int cur = t & 1;
    const int nxt = cur ^ 1;
    const int t1 = (t + 1 < NT) ? t + 1 : NT - 1;  // clamp: redundant re-stage,
    const int t2 = (t + 2 < NT) ? t + 2 : NT - 1;  // keeps vmcnt counts uniform
    // ---- ph0: kc0, m-half 0 ----
    LOAD_AF(cur, 0, 0); LOAD_BF(cur, 0);
    STAGE_A(nxt, 1, t1);           // buf[nxt].Akc1: last read t-1.ph3 (barrier'd)
    BAR(); WAIT_LGKM0();
    MFMA_BLK(0);
    BAR(); SCB();                  // Bkc0(cur) fully read by all waves
    // ---- ph1: kc0, m-half 1 (bfr reused from ph0) ----
    LOAD_AF(cur, 0, 1);
    STAGE_B(cur, 0, t2);           // overwrites Bkc0(cur): freed at ph0 barrier
    BAR(); WAIT_LGKM0();
    MFMA_BLK(1);
    BAR(); SCB();                  // Akc0(cur) fully read
    // ---- ph2: kc1, m-half 0 ----
    LOAD_AF(cur, 1, 0); LOAD_BF(cur, 1);
    STAGE_A(cur, 0, t2);           // overwrites Akc0(cur): freed at ph1 barrier
    BAR(); WAIT_LGKM0();
    MFMA_BLK(0);
    BAR(); SCB();                  // Bkc1(cur) fully read
    // ---- ph3: kc1, m-half 1 ----
    LOAD_AF(cur, 1, 1);
    STAGE_B(cur, 1, t2);           // overwrites Bkc1(cur): freed at ph2 barrier
    BAR(); WAIT_LGKM0();
    MFMA_BLK(1);
    // counted wait: newest 3 regions (tile t+2 partial) may stay in flight;
    // everything through Akc1(t+1) complete -> tile t+1 resident.
    asm volatile("s_waitcnt vmcnt(6)" ::: "memory");
    BAR(); SCB();                  // Akc1(cur) fully read
  }
  asm volatile("s_waitcnt vmcnt(0)" ::: "memory");  // drain tail stages

  // ---- epilogue: ni == gate (0=i,1=g,2=f,3=o); lane's j fixed ----
  // W-packed row = bn*256 + wn*64 + ni*16 + jl decodes (pack_w layout) to
  // j = (bn*2 + (wn>>1))*32 + (wn&1)*16 + jl, gate = ni.
  const int jl = lane & 15;
  const int rq = (lane >> 4) << 2;
  const int j  = (bn * 2 + (wn >> 1)) * 32 + (wn & 1) * 16 + jl;
  float bv[4];
#pragma unroll
  for (int ni = 0; ni < 4; ++ni)
    bv[ni] = bias[bn * 256 + wn * 64 + ni * 16 + jl];

#pragma unroll
  for (int mi = 0; mi < 8; ++mi) {
    const int row0 = bm * 256 + wm * 128 + (mi >> 2) * 64 + (mi & 3) * 16 + rq;
#pragma unroll
    for (int r = 0; r < 4; ++r) {
      int row = row0 + r;
      float iv = fast_sigmoid(acc[mi][0][r] + bv[0]);
      float gv = fast_tanh   (acc[mi][1][r] + bv[1]);
      float fv = fast_sigmoid(acc[mi][2][r] + bv[2]);
      float ov = fast_sigmoid(acc[mi][3][r] + bv[3]);
      float cold = Cin[(size_t)row * HIDN + j];
      float cnew = fv * cold + iv * gv;
      Hout[(size_t)row * HIDN + j] = ov * fast_tanh(cnew);
      Cout[(size_t)row * HIDN + j] = cnew;
    }
  }
}

// ---------------- launch ----------------

extern "C" void kernel_launch(void* const* d_in, const int* in_sizes, int n_in,
                              void* d_out, int out_size, void* d_ws, size_t ws_size,
                              hipStream_t stream) {
  const float* x   = (const float*)d_in[0];
  const float* h   = (const float*)d_in[1];
  const float* c   = (const float*)d_in[2];
  const float* Wxi = (const float*)d_in[3];  const float* bxi = (const float*)d_in[4];
  const float* Wxo = (const float*)d_in[5];  const float* bxo = (const float*)d_in[6];
  const float* Wxf = (const float*)d_in[7];  const float* bxf = (const float*)d_in[8];
  const float* Wxg = (const float*)d_in[9];  const float* bxg = (const float*)d_in[10];
  const float* Whi = (const float*)d_in[11]; const float* bhi = (const float*)d_in[12];
  const float* Who = (const float*)d_in[13]; const float* bho = (const float*)d_in[14];
  const float* Whf = (const float*)d_in[15]; const float* bhf = (const float*)d_in[16];
  const float* Whg = (const float*)d_in[17]; const float* bhg = (const float*)d_in[18];

  char* ws = (char*)d_ws;
  unsigned short* Apack = (unsigned short*)ws;                              // 32 MB
  unsigned short* Wpack = (unsigned short*)(ws + (size_t)BATCH * KDIM * 2); // 4 MB
  float* biasp = (float*)(ws + (size_t)BATCH * KDIM * 2 + (size_t)NPK * KDIM * 2);

  pack_a<<<(BATCH * KDIM / 8) / 256, 256, 0, stream>>>(x, h, Apack);

  GatePtrs P;
  P.wx[0] = Wxi; P.wx[1] = Wxg; P.wx[2] = Wxf; P.wx[3] = Wxo;
  P.wh[0] = Whi; P.wh[1] = Whg; P.wh[2] = Whf; P.wh[3] = Who;
  P.bx[0] = bxi; P.bx[1] = bxg; P.bx[2] = bxf; P.bx[3] = bxo;
  P.bh[0] = bhi; P.bh[1] = bhg; P.bh[2] = bhf; P.bh[3] = bho;
  pack_w<<<(NPK * KDIM / 8) / 256, 256, 0, stream>>>(P, Wpack, biasp);

  float* Hout = (float*)d_out;
  float* Cout = Hout + (size_t)BATCH * HIDN;
  lstm_gemm<<<dim3((BATCH / BM) * (NPK / BN)), 512, 0, stream>>>(
      Apack, Wpack, biasp, c, Hout, Cout);
}